// Round 3
// baseline (1263.444 us; speedup 1.0000x reference)
//
#include <hip/hip_runtime.h>

#define NN_ 131072
#define E_  2097152
#define B_  64
#define K_  20480
#define H_  512
#define EPS_ 1e-6f

// ---------------- graph preprocessing ----------------

__global__ __launch_bounds__(256) void k_deg_hist(const int* __restrict__ ei, const float* __restrict__ ew,
                                                  float* __restrict__ deg, int* __restrict__ cnt) {
  int e = blockIdx.x * 256 + threadIdx.x;
  if (e >= E_) return;
  int r = ei[e];
  atomicAdd(&deg[r], ew[e]);
  atomicAdd(&cnt[r], 1);
}

__global__ __launch_bounds__(256) void k_dinv(const float* __restrict__ deg, float* __restrict__ dinv) {
  int n = blockIdx.x * 256 + threadIdx.x;
  if (n >= NN_) return;
  float d = deg[n];
  dinv[n] = (d > 0.f) ? rsqrtf(d + EPS_) : 0.f;
}

__global__ __launch_bounds__(256) void k_scan_a(const int* __restrict__ cnt, int* __restrict__ bsum) {
  __shared__ int s[256];
  int t = threadIdx.x, b = blockIdx.x;
  s[t] = cnt[b * 512 + t] + cnt[b * 512 + 256 + t];
  __syncthreads();
  for (int off = 128; off > 0; off >>= 1) {
    if (t < off) s[t] += s[t + off];
    __syncthreads();
  }
  if (t == 0) bsum[b] = s[0];
}

__global__ __launch_bounds__(256) void k_scan_b(const int* __restrict__ bsum, int* __restrict__ boff) {
  __shared__ int s[256];
  int t = threadIdx.x;
  int orig = bsum[t];
  s[t] = orig;
  __syncthreads();
  for (int off = 1; off < 256; off <<= 1) {
    int v = (t >= off) ? s[t - off] : 0;
    __syncthreads();
    s[t] += v;
    __syncthreads();
  }
  boff[t] = s[t] - orig;   // exclusive
}

__global__ __launch_bounds__(256) void k_scan_c(const int* __restrict__ cnt, const int* __restrict__ boff,
                                                int* __restrict__ rowstart) {
  __shared__ int s[256];
  int t = threadIdx.x, b = blockIdx.x;
  int base = b * 512;
  int c0 = cnt[base + 2 * t], c1 = cnt[base + 2 * t + 1];
  int pair = c0 + c1;
  s[t] = pair;
  __syncthreads();
  for (int off = 1; off < 256; off <<= 1) {
    int v = (t >= off) ? s[t - off] : 0;
    __syncthreads();
    s[t] += v;
    __syncthreads();
  }
  int excl = s[t] - pair + boff[b];
  rowstart[base + 2 * t] = excl;
  rowstart[base + 2 * t + 1] = excl + c0;
}

__global__ __launch_bounds__(256) void k_build(const int* __restrict__ ei, const float* __restrict__ ew,
                                               const float* __restrict__ dinv, const int* __restrict__ rowstart,
                                               int* __restrict__ fill, int* __restrict__ col_s,
                                               float* __restrict__ wn_s) {
  int e = blockIdx.x * 256 + threadIdx.x;
  if (e >= E_) return;
  int r = ei[e], c = ei[E_ + e];
  float w = ew[e] * dinv[r] * dinv[c];
  int pos = rowstart[r] + atomicAdd(&fill[r], 1);
  col_s[pos] = c;
  wn_s[pos] = w;
}

// ---------------- conv1 (complex 1x1 conv + ReLU) ----------------
// Y layout: [NN][20]  (0..9 real, 10..19 imag)

__global__ __launch_bounds__(256) void k_conv1(const float* __restrict__ xr, const float* __restrict__ xi,
                                               const float* __restrict__ wr_g, const float* __restrict__ wi_g,
                                               const float* __restrict__ br_g, const float* __restrict__ bi_g,
                                               float* __restrict__ Y) {
  __shared__ float wr[100], wi[100], br[10], bi[10];
  int t = threadIdx.x;
  if (t < 100) { wr[t] = wr_g[t]; wi[t] = wi_g[t]; }
  if (t < 10)  { br[t] = br_g[t]; bi[t] = bi_g[t]; }
  __syncthreads();
  int n = blockIdx.x * 256 + t;
  float xrv[10], xiv[10];
  const float2* a = (const float2*)(xr + (size_t)n * 10);
  const float2* b2 = (const float2*)(xi + (size_t)n * 10);
#pragma unroll
  for (int i = 0; i < 5; i++) {
    float2 v = a[i];  xrv[2 * i] = v.x; xrv[2 * i + 1] = v.y;
    float2 u = b2[i]; xiv[2 * i] = u.x; xiv[2 * i + 1] = u.y;
  }
  float out[20];
#pragma unroll
  for (int c = 0; c < 10; c++) {
    float ar = br[c], ai = bi[c];
#pragma unroll
    for (int tt = 0; tt < 10; tt++) {
      float wrc = wr[c * 10 + tt], wic = wi[c * 10 + tt];
      ar += xrv[tt] * wrc - xiv[tt] * wic;
      ai += xrv[tt] * wic + xiv[tt] * wrc;
    }
    out[c] = fmaxf(ar, 0.f);
    out[10 + c] = fmaxf(ai, 0.f);
  }
  float4* yp = (float4*)(Y + (size_t)n * 20);
#pragma unroll
  for (int i = 0; i < 5; i++)
    yp[i] = make_float4(out[4 * i], out[4 * i + 1], out[4 * i + 2], out[4 * i + 3]);
}

// ---------------- Laplacian pass 1: T1 = Y - S(Y) ----------------

__global__ __launch_bounds__(256) void k_lap1(const float* __restrict__ Y, const int* __restrict__ col_s,
                                              const float* __restrict__ wn_s, const int* __restrict__ rowstart,
                                              const int* __restrict__ cnt, float* __restrict__ T1) {
  int n = blockIdx.x * 256 + threadIdx.x;
  float acc[20];
#pragma unroll
  for (int j = 0; j < 20; j++) acc[j] = 0.f;
  int e0 = rowstart[n], ec = cnt[n];
  for (int i = 0; i < ec; i++) {
    int c = col_s[e0 + i];
    float w = wn_s[e0 + i];
    const float4* yp = (const float4*)(Y + (size_t)c * 20);
#pragma unroll
    for (int q = 0; q < 5; q++) {
      float4 v = yp[q];
      acc[4 * q]     += w * v.x;
      acc[4 * q + 1] += w * v.y;
      acc[4 * q + 2] += w * v.z;
      acc[4 * q + 3] += w * v.w;
    }
  }
  const float4* yn = (const float4*)(Y + (size_t)n * 20);
  float4* tp = (float4*)(T1 + (size_t)n * 20);
#pragma unroll
  for (int q = 0; q < 5; q++) {
    float4 v = yn[q];
    tp[q] = make_float4(v.x - acc[4 * q], v.y - acc[4 * q + 1],
                        v.z - acc[4 * q + 2], v.w - acc[4 * q + 3]);
  }
}

// ---------------- Laplacian pass 2 + Chebyshev combine + ReLU ----------------

__global__ __launch_bounds__(256) void k_lap2cheb(const float* __restrict__ Y, const float* __restrict__ T1,
                                                  const int* __restrict__ col_s, const float* __restrict__ wn_s,
                                                  const int* __restrict__ rowstart, const int* __restrict__ cnt,
                                                  const float* __restrict__ cw_g, const float* __restrict__ cb_g,
                                                  float* __restrict__ zr, float* __restrict__ zi) {
  __shared__ float cw[300], cb[10];
  int t = threadIdx.x;
  for (int j = t; j < 300; j += 256) cw[j] = cw_g[j];   // 300 > blockDim: strided load (bug fix)
  if (t < 10)  cb[t] = cb_g[t];
  __syncthreads();
  int n = blockIdx.x * 256 + t;
  float acc[20];
#pragma unroll
  for (int j = 0; j < 20; j++) acc[j] = 0.f;
  int e0 = rowstart[n], ec = cnt[n];
  for (int i = 0; i < ec; i++) {
    int c = col_s[e0 + i];
    float w = wn_s[e0 + i];
    const float4* tp = (const float4*)(T1 + (size_t)c * 20);
#pragma unroll
    for (int q = 0; q < 5; q++) {
      float4 v = tp[q];
      acc[4 * q]     += w * v.x;
      acc[4 * q + 1] += w * v.y;
      acc[4 * q + 2] += w * v.z;
      acc[4 * q + 3] += w * v.w;
    }
  }
  float t0[20], t1v[20], t2[20];
  const float4* yn = (const float4*)(Y + (size_t)n * 20);
  const float4* tn = (const float4*)(T1 + (size_t)n * 20);
#pragma unroll
  for (int q = 0; q < 5; q++) {
    float4 v = yn[q]; t0[4 * q] = v.x; t0[4 * q + 1] = v.y; t0[4 * q + 2] = v.z; t0[4 * q + 3] = v.w;
    float4 u = tn[q]; t1v[4 * q] = u.x; t1v[4 * q + 1] = u.y; t1v[4 * q + 2] = u.z; t1v[4 * q + 3] = u.w;
  }
#pragma unroll
  for (int j = 0; j < 20; j++) t2[j] = 2.f * (t1v[j] - acc[j]) - t0[j];

  float outr[10], outi[10];
#pragma unroll
  for (int o = 0; o < 10; o++) { outr[o] = cb[o]; outi[o] = 0.f; }
#pragma unroll
  for (int i = 0; i < 10; i++) {
#pragma unroll
    for (int o = 0; o < 10; o++) {
      float w0 = cw[i * 10 + o], w1 = cw[100 + i * 10 + o], w2 = cw[200 + i * 10 + o];
      outr[o] += t0[i] * w0 + t1v[i] * w1 + t2[i] * w2;
      outi[o] += t0[10 + i] * w0 + t1v[10 + i] * w1 + t2[10 + i] * w2;
    }
  }
  float2* zrp = (float2*)(zr + (size_t)n * 10);
  float2* zip = (float2*)(zi + (size_t)n * 10);
#pragma unroll
  for (int q = 0; q < 5; q++) {
    zrp[q] = make_float2(fmaxf(outr[2 * q], 0.f), fmaxf(outr[2 * q + 1], 0.f));
    zip[q] = make_float2(fmaxf(outi[2 * q], 0.f), fmaxf(outi[2 * q + 1], 0.f));
  }
}

// ---------------- fc1 complex GEMM (split-K, partials) ----------------
// grid (8 h-tiles, 64 k-chunks); tile 64b x 64h; chunk = 320 = 10 iters of 32
// pacc layout: [kc][b][h][2]

__global__ __launch_bounds__(256) void k_fc1(const float* __restrict__ zr, const float* __restrict__ zi,
                                             const float* __restrict__ Wr, const float* __restrict__ Wi,
                                             float* __restrict__ pacc) {
  __shared__ float zsr[64][36], zsi[64][36], wsr[64][36], wsi[64][36];
  int t = threadIdx.x;
  int hb = blockIdx.x;          // 0..7
  int kc = blockIdx.y;          // 0..63
  int H0 = hb * 64;
  int tx = t & 15, ty = t >> 4; // tx: h-dim, ty: b-dim (0..15)

  float ur[4][4], ui[4][4];
#pragma unroll
  for (int i = 0; i < 4; i++)
#pragma unroll
    for (int j = 0; j < 4; j++) { ur[i][j] = 0.f; ui[i][j] = 0.f; }

  for (int it = 0; it < 10; it++) {
    int JJ = kc * 320 + it * 32;
    __syncthreads();
#pragma unroll
    for (int l = 0; l < 2; l++) {
      int f = t + l * 256;          // float4 id 0..511
      int row = f >> 3;             // 0..63
      int j4 = (f & 7) << 2;        // 0..28
      float4 vz = *(const float4*)(zr + row * K_ + JJ + j4);
      float4 vi = *(const float4*)(zi + row * K_ + JJ + j4);
      float4 vr = *(const float4*)(Wr + (H0 + row) * K_ + JJ + j4);
      float4 vw = *(const float4*)(Wi + (H0 + row) * K_ + JJ + j4);
      *(float4*)&zsr[row][j4] = vz;
      *(float4*)&zsi[row][j4] = vi;
      *(float4*)&wsr[row][j4] = vr;
      *(float4*)&wsi[row][j4] = vw;
    }
    __syncthreads();
#pragma unroll
    for (int j0 = 0; j0 < 32; j0 += 4) {
      float4 za[4], zb[4], wa[4], wb[4];
#pragma unroll
      for (int bb = 0; bb < 4; bb++) {
        za[bb] = *(const float4*)&zsr[ty + 16 * bb][j0];
        zb[bb] = *(const float4*)&zsi[ty + 16 * bb][j0];
      }
#pragma unroll
      for (int hh = 0; hh < 4; hh++) {
        wa[hh] = *(const float4*)&wsr[tx + 16 * hh][j0];
        wb[hh] = *(const float4*)&wsi[tx + 16 * hh][j0];
      }
#pragma unroll
      for (int bb = 0; bb < 4; bb++)
#pragma unroll
        for (int hh = 0; hh < 4; hh++) {
          ur[bb][hh] += za[bb].x * wa[hh].x + za[bb].y * wa[hh].y + za[bb].z * wa[hh].z + za[bb].w * wa[hh].w
                      - zb[bb].x * wb[hh].x - zb[bb].y * wb[hh].y - zb[bb].z * wb[hh].z - zb[bb].w * wb[hh].w;
          ui[bb][hh] += za[bb].x * wb[hh].x + za[bb].y * wb[hh].y + za[bb].z * wb[hh].z + za[bb].w * wb[hh].w
                      + zb[bb].x * wa[hh].x + zb[bb].y * wa[hh].y + zb[bb].z * wa[hh].z + zb[bb].w * wa[hh].w;
        }
    }
  }
#pragma unroll
  for (int bb = 0; bb < 4; bb++) {
    int b = ty + 16 * bb;
#pragma unroll
    for (int hh = 0; hh < 4; hh++) {
      int h = H0 + tx + 16 * hh;
      *(float2*)&pacc[(((size_t)kc * 64 + b) * 512 + h) * 2] = make_float2(ur[bb][hh], ui[bb][hh]);
    }
  }
}

// ---------------- reduce partials + fc1 bias/ReLU + actor/critic head ----------------

__global__ __launch_bounds__(256) void k_head(const float* __restrict__ pacc,
                                              const float* __restrict__ br, const float* __restrict__ bi,
                                              const float* __restrict__ actor_w, const float* __restrict__ actor_b,
                                              const float* __restrict__ critic_w, const float* __restrict__ critic_b,
                                              float* __restrict__ out) {
  __shared__ float urs[512], uis[512];
  int b = blockIdx.x, t = threadIdx.x;
  float s0r = 0, s0i = 0, s1r = 0, s1i = 0;
  for (int kc = 0; kc < 64; kc++) {
    float4 v = *(const float4*)&pacc[(((size_t)kc * 64 + b) * 512 + 2 * t) * 2];
    s0r += v.x; s0i += v.y; s1r += v.z; s1i += v.w;
  }
  urs[2 * t]     = fmaxf(s0r + br[2 * t], 0.f);
  uis[2 * t]     = fmaxf(s0i + bi[2 * t], 0.f);
  urs[2 * t + 1] = fmaxf(s1r + br[2 * t + 1], 0.f);
  uis[2 * t + 1] = fmaxf(s1i + bi[2 * t + 1], 0.f);
  __syncthreads();
  if (t < 33) {
    const float* w = (t < 32) ? (actor_w + t * 1024) : critic_w;
    float acc = (t < 32) ? actor_b[t] : critic_b[0];
    for (int k = 0; k < 512; k++)
      acc += urs[k] * w[k] + uis[k] * w[512 + k];
    if (t < 32) out[b * 32 + t] = acc;
    else        out[2048 + b] = acc;
  }
}

// ---------------- launch ----------------

extern "C" void kernel_launch(void* const* d_in, const int* in_sizes, int n_in,
                              void* d_out, int out_size, void* d_ws, size_t ws_size,
                              hipStream_t stream) {
  const float* xr   = (const float*)d_in[0];
  const float* xi   = (const float*)d_in[1];
  const float* ew   = (const float*)d_in[2];
  const float* c1wr = (const float*)d_in[3];
  const float* c1wi = (const float*)d_in[4];
  const float* c1br = (const float*)d_in[5];
  const float* c1bi = (const float*)d_in[6];
  const float* chw  = (const float*)d_in[7];
  const float* chb  = (const float*)d_in[8];
  const float* f1wr = (const float*)d_in[9];
  const float* f1wi = (const float*)d_in[10];
  const float* f1br = (const float*)d_in[11];
  const float* f1bi = (const float*)d_in[12];
  const float* cw   = (const float*)d_in[13];
  const float* cb   = (const float*)d_in[14];
  const float* aw   = (const float*)d_in[15];
  const float* ab   = (const float*)d_in[16];
  const int*   ei   = (const int*)d_in[17];
  float* out = (float*)d_out;

  char* ws = (char*)d_ws;
  size_t off = 0;
  auto alloc = [&](size_t bytes) { char* p = ws + off; off += (bytes + 255) & ~(size_t)255; return p; };
  float* deg      = (float*)alloc((size_t)NN_ * 4);   // zeroed (deg, cnt, fill contiguous)
  int*   cnt      = (int*)  alloc((size_t)NN_ * 4);   // zeroed
  int*   fill     = (int*)  alloc((size_t)NN_ * 4);   // zeroed
  int*   rowstart = (int*)  alloc((size_t)NN_ * 4);
  float* dinv     = (float*)alloc((size_t)NN_ * 4);
  int*   bsum     = (int*)  alloc(1024);
  int*   boff     = (int*)  alloc(1024);
  int*   col_s    = (int*)  alloc((size_t)E_ * 4);
  float* wn_s     = (float*)alloc((size_t)E_ * 4);
  float* zr       = (float*)alloc((size_t)NN_ * 10 * 4);
  float* zi       = (float*)alloc((size_t)NN_ * 10 * 4);
  float* Y        = (float*)alloc((size_t)NN_ * 20 * 4);
  float* T1       = (float*)alloc((size_t)NN_ * 20 * 4);
  // pacc (16 MB) aliases Y+T1 (21 MB): both dead once k_fc1 starts
  float* pacc = Y;

  hipMemsetAsync(deg, 0, (size_t)NN_ * 4 * 3, stream);  // deg, cnt, fill

  k_deg_hist<<<E_ / 256, 256, 0, stream>>>(ei, ew, deg, cnt);
  k_dinv<<<NN_ / 256, 256, 0, stream>>>(deg, dinv);
  k_scan_a<<<256, 256, 0, stream>>>(cnt, bsum);
  k_scan_b<<<1, 256, 0, stream>>>(bsum, boff);
  k_scan_c<<<256, 256, 0, stream>>>(cnt, boff, rowstart);
  k_build<<<E_ / 256, 256, 0, stream>>>(ei, ew, dinv, rowstart, fill, col_s, wn_s);
  k_conv1<<<NN_ / 256, 256, 0, stream>>>(xr, xi, c1wr, c1wi, c1br, c1bi, Y);
  k_lap1<<<NN_ / 256, 256, 0, stream>>>(Y, col_s, wn_s, rowstart, cnt, T1);
  k_lap2cheb<<<NN_ / 256, 256, 0, stream>>>(Y, T1, col_s, wn_s, rowstart, cnt, chw, chb, zr, zi);
  k_fc1<<<dim3(8, 64), 256, 0, stream>>>(zr, zi, f1wr, f1wi, pacc);
  k_head<<<B_, 256, 0, stream>>>(pacc, f1br, f1bi, aw, ab, cw, cb, out);
}

// Round 4
// 754.060 us; speedup vs baseline: 1.6755x; 1.6755x over previous
//
#include <hip/hip_runtime.h>

#define NN_ 131072
#define E_  2097152
#define B_  64
#define K_  20480
#define H_  512
#define EPS_ 1e-6f

// ---------------- graph preprocessing ----------------

__global__ __launch_bounds__(256) void k_deg_hist(const int* __restrict__ ei, const float* __restrict__ ew,
                                                  float* __restrict__ deg, int* __restrict__ cnt) {
  int e = blockIdx.x * 256 + threadIdx.x;
  if (e >= E_) return;
  int r = ei[e];
  atomicAdd(&deg[r], ew[e]);
  atomicAdd(&cnt[r], 1);
}

__global__ __launch_bounds__(256) void k_dinv(const float* __restrict__ deg, float* __restrict__ dinv) {
  int n = blockIdx.x * 256 + threadIdx.x;
  if (n >= NN_) return;
  float d = deg[n];
  dinv[n] = (d > 0.f) ? rsqrtf(d + EPS_) : 0.f;
}

__global__ __launch_bounds__(256) void k_scan_a(const int* __restrict__ cnt, int* __restrict__ bsum) {
  __shared__ int s[256];
  int t = threadIdx.x, b = blockIdx.x;
  s[t] = cnt[b * 512 + t] + cnt[b * 512 + 256 + t];
  __syncthreads();
  for (int off = 128; off > 0; off >>= 1) {
    if (t < off) s[t] += s[t + off];
    __syncthreads();
  }
  if (t == 0) bsum[b] = s[0];
}

__global__ __launch_bounds__(256) void k_scan_b(const int* __restrict__ bsum, int* __restrict__ boff) {
  __shared__ int s[256];
  int t = threadIdx.x;
  int orig = bsum[t];
  s[t] = orig;
  __syncthreads();
  for (int off = 1; off < 256; off <<= 1) {
    int v = (t >= off) ? s[t - off] : 0;
    __syncthreads();
    s[t] += v;
    __syncthreads();
  }
  boff[t] = s[t] - orig;   // exclusive
}

__global__ __launch_bounds__(256) void k_scan_c(const int* __restrict__ cnt, const int* __restrict__ boff,
                                                int* __restrict__ rowstart) {
  __shared__ int s[256];
  int t = threadIdx.x, b = blockIdx.x;
  int base = b * 512;
  int c0 = cnt[base + 2 * t], c1 = cnt[base + 2 * t + 1];
  int pair = c0 + c1;
  s[t] = pair;
  __syncthreads();
  for (int off = 1; off < 256; off <<= 1) {
    int v = (t >= off) ? s[t - off] : 0;
    __syncthreads();
    s[t] += v;
    __syncthreads();
  }
  int excl = s[t] - pair + boff[b];
  rowstart[base + 2 * t] = excl;
  rowstart[base + 2 * t + 1] = excl + c0;
}

__global__ __launch_bounds__(256) void k_build(const int* __restrict__ ei, const float* __restrict__ ew,
                                               const float* __restrict__ dinv, const int* __restrict__ rowstart,
                                               int* __restrict__ fill, int* __restrict__ col_s,
                                               float* __restrict__ wn_s) {
  int e = blockIdx.x * 256 + threadIdx.x;
  if (e >= E_) return;
  int r = ei[e], c = ei[E_ + e];
  float w = ew[e] * dinv[r] * dinv[c];
  int pos = rowstart[r] + atomicAdd(&fill[r], 1);
  col_s[pos] = c;
  wn_s[pos] = w;
}

// ---------------- conv1 (complex 1x1 conv + ReLU) ----------------
// Y layout: [NN][20]  (0..9 real, 10..19 imag)

__global__ __launch_bounds__(256) void k_conv1(const float* __restrict__ xr, const float* __restrict__ xi,
                                               const float* __restrict__ wr_g, const float* __restrict__ wi_g,
                                               const float* __restrict__ br_g, const float* __restrict__ bi_g,
                                               float* __restrict__ Y) {
  __shared__ float wr[100], wi[100], br[10], bi[10];
  int t = threadIdx.x;
  if (t < 100) { wr[t] = wr_g[t]; wi[t] = wi_g[t]; }
  if (t < 10)  { br[t] = br_g[t]; bi[t] = bi_g[t]; }
  __syncthreads();
  int n = blockIdx.x * 256 + t;
  float xrv[10], xiv[10];
  const float2* a = (const float2*)(xr + (size_t)n * 10);
  const float2* b2 = (const float2*)(xi + (size_t)n * 10);
#pragma unroll
  for (int i = 0; i < 5; i++) {
    float2 v = a[i];  xrv[2 * i] = v.x; xrv[2 * i + 1] = v.y;
    float2 u = b2[i]; xiv[2 * i] = u.x; xiv[2 * i + 1] = u.y;
  }
  float out[20];
#pragma unroll
  for (int c = 0; c < 10; c++) {
    float ar = br[c], ai = bi[c];
#pragma unroll
    for (int tt = 0; tt < 10; tt++) {
      float wrc = wr[c * 10 + tt], wic = wi[c * 10 + tt];
      ar += xrv[tt] * wrc - xiv[tt] * wic;
      ai += xrv[tt] * wic + xiv[tt] * wrc;
    }
    out[c] = fmaxf(ar, 0.f);
    out[10 + c] = fmaxf(ai, 0.f);
  }
  float4* yp = (float4*)(Y + (size_t)n * 20);
#pragma unroll
  for (int i = 0; i < 5; i++)
    yp[i] = make_float4(out[4 * i], out[4 * i + 1], out[4 * i + 2], out[4 * i + 3]);
}

// ---------------- Laplacian pass 1: T1 = Y - S(Y) ----------------

__global__ __launch_bounds__(256) void k_lap1(const float* __restrict__ Y, const int* __restrict__ col_s,
                                              const float* __restrict__ wn_s, const int* __restrict__ rowstart,
                                              const int* __restrict__ cnt, float* __restrict__ T1) {
  int n = blockIdx.x * 256 + threadIdx.x;
  float acc[20];
#pragma unroll
  for (int j = 0; j < 20; j++) acc[j] = 0.f;
  int e0 = rowstart[n], ec = cnt[n];
  for (int i = 0; i < ec; i++) {
    int c = col_s[e0 + i];
    float w = wn_s[e0 + i];
    const float4* yp = (const float4*)(Y + (size_t)c * 20);
#pragma unroll
    for (int q = 0; q < 5; q++) {
      float4 v = yp[q];
      acc[4 * q]     += w * v.x;
      acc[4 * q + 1] += w * v.y;
      acc[4 * q + 2] += w * v.z;
      acc[4 * q + 3] += w * v.w;
    }
  }
  const float4* yn = (const float4*)(Y + (size_t)n * 20);
  float4* tp = (float4*)(T1 + (size_t)n * 20);
#pragma unroll
  for (int q = 0; q < 5; q++) {
    float4 v = yn[q];
    tp[q] = make_float4(v.x - acc[4 * q], v.y - acc[4 * q + 1],
                        v.z - acc[4 * q + 2], v.w - acc[4 * q + 3]);
  }
}

// ---------------- Laplacian pass 2 + Chebyshev combine + ReLU ----------------

__global__ __launch_bounds__(256) void k_lap2cheb(const float* __restrict__ Y, const float* __restrict__ T1,
                                                  const int* __restrict__ col_s, const float* __restrict__ wn_s,
                                                  const int* __restrict__ rowstart, const int* __restrict__ cnt,
                                                  const float* __restrict__ cw_g, const float* __restrict__ cb_g,
                                                  float* __restrict__ zr, float* __restrict__ zi) {
  __shared__ float cw[300], cb[10];
  int t = threadIdx.x;
  for (int j = t; j < 300; j += 256) cw[j] = cw_g[j];   // 300 > blockDim: strided load
  if (t < 10)  cb[t] = cb_g[t];
  __syncthreads();
  int n = blockIdx.x * 256 + t;
  float acc[20];
#pragma unroll
  for (int j = 0; j < 20; j++) acc[j] = 0.f;
  int e0 = rowstart[n], ec = cnt[n];
  for (int i = 0; i < ec; i++) {
    int c = col_s[e0 + i];
    float w = wn_s[e0 + i];
    const float4* tp = (const float4*)(T1 + (size_t)c * 20);
#pragma unroll
    for (int q = 0; q < 5; q++) {
      float4 v = tp[q];
      acc[4 * q]     += w * v.x;
      acc[4 * q + 1] += w * v.y;
      acc[4 * q + 2] += w * v.z;
      acc[4 * q + 3] += w * v.w;
    }
  }
  float t0[20], t1v[20], t2[20];
  const float4* yn = (const float4*)(Y + (size_t)n * 20);
  const float4* tn = (const float4*)(T1 + (size_t)n * 20);
#pragma unroll
  for (int q = 0; q < 5; q++) {
    float4 v = yn[q]; t0[4 * q] = v.x; t0[4 * q + 1] = v.y; t0[4 * q + 2] = v.z; t0[4 * q + 3] = v.w;
    float4 u = tn[q]; t1v[4 * q] = u.x; t1v[4 * q + 1] = u.y; t1v[4 * q + 2] = u.z; t1v[4 * q + 3] = u.w;
  }
#pragma unroll
  for (int j = 0; j < 20; j++) t2[j] = 2.f * (t1v[j] - acc[j]) - t0[j];

  float outr[10], outi[10];
#pragma unroll
  for (int o = 0; o < 10; o++) { outr[o] = cb[o]; outi[o] = 0.f; }
#pragma unroll
  for (int i = 0; i < 10; i++) {
#pragma unroll
    for (int o = 0; o < 10; o++) {
      float w0 = cw[i * 10 + o], w1 = cw[100 + i * 10 + o], w2 = cw[200 + i * 10 + o];
      outr[o] += t0[i] * w0 + t1v[i] * w1 + t2[i] * w2;
      outi[o] += t0[10 + i] * w0 + t1v[10 + i] * w1 + t2[10 + i] * w2;
    }
  }
  float2* zrp = (float2*)(zr + (size_t)n * 10);
  float2* zip = (float2*)(zi + (size_t)n * 10);
#pragma unroll
  for (int q = 0; q < 5; q++) {
    zrp[q] = make_float2(fmaxf(outr[2 * q], 0.f), fmaxf(outr[2 * q + 1], 0.f));
    zip[q] = make_float2(fmaxf(outi[2 * q], 0.f), fmaxf(outi[2 * q + 1], 0.f));
  }
}

// ---------------- fc1 complex GEMM (split-K, partials) ----------------
// grid (8 h-tiles, 64 k-chunks); tile 64b x 64h; chunk = 320 = 10 iters of 32
// pacc layout: [kc][b][h][2]
// R4: spill fix — unroll-1 on it/j0 loops, hh split in halves.
// Live regs ~ 32 acc + 32 za/zb + 16 w + addr ≈ 100 (was >512 wanted -> 893 MB spill WRITE)

__global__ __launch_bounds__(256) void k_fc1(const float* __restrict__ zr, const float* __restrict__ zi,
                                             const float* __restrict__ Wr, const float* __restrict__ Wi,
                                             float* __restrict__ pacc) {
  __shared__ float zsr[64][36], zsi[64][36], wsr[64][36], wsi[64][36];
  int t = threadIdx.x;
  int hb = blockIdx.x;          // 0..7
  int kc = blockIdx.y;          // 0..63
  int H0 = hb * 64;
  int tx = t & 15, ty = t >> 4; // tx: h-dim, ty: b-dim (0..15)

  float ur[4][4], ui[4][4];
#pragma unroll
  for (int i = 0; i < 4; i++)
#pragma unroll
    for (int j = 0; j < 4; j++) { ur[i][j] = 0.f; ui[i][j] = 0.f; }

#pragma unroll 1
  for (int it = 0; it < 10; it++) {
    int JJ = kc * 320 + it * 32;
    __syncthreads();
#pragma unroll
    for (int l = 0; l < 2; l++) {
      int f = t + l * 256;          // float4 id 0..511
      int row = f >> 3;             // 0..63
      int j4 = (f & 7) << 2;        // 0..28
      float4 vz = *(const float4*)(zr + row * K_ + JJ + j4);
      float4 vi = *(const float4*)(zi + row * K_ + JJ + j4);
      float4 vr = *(const float4*)(Wr + (H0 + row) * K_ + JJ + j4);
      float4 vw = *(const float4*)(Wi + (H0 + row) * K_ + JJ + j4);
      *(float4*)&zsr[row][j4] = vz;
      *(float4*)&zsi[row][j4] = vi;
      *(float4*)&wsr[row][j4] = vr;
      *(float4*)&wsi[row][j4] = vw;
    }
    __syncthreads();
#pragma unroll 1
    for (int j0 = 0; j0 < 32; j0 += 4) {
      float4 za[4], zb[4];
#pragma unroll
      for (int bb = 0; bb < 4; bb++) {
        za[bb] = *(const float4*)&zsr[ty + 16 * bb][j0];
        zb[bb] = *(const float4*)&zsi[ty + 16 * bb][j0];
      }
#pragma unroll
      for (int hp = 0; hp < 2; hp++) {
        int h0 = 2 * hp, h1 = 2 * hp + 1;
        float4 wa0 = *(const float4*)&wsr[tx + 16 * h0][j0];
        float4 wb0 = *(const float4*)&wsi[tx + 16 * h0][j0];
        float4 wa1 = *(const float4*)&wsr[tx + 16 * h1][j0];
        float4 wb1 = *(const float4*)&wsi[tx + 16 * h1][j0];
#pragma unroll
        for (int bb = 0; bb < 4; bb++) {
          float4 a = za[bb], b = zb[bb];
          ur[bb][h0] += a.x * wa0.x + a.y * wa0.y + a.z * wa0.z + a.w * wa0.w
                      - b.x * wb0.x - b.y * wb0.y - b.z * wb0.z - b.w * wb0.w;
          ui[bb][h0] += a.x * wb0.x + a.y * wb0.y + a.z * wb0.z + a.w * wb0.w
                      + b.x * wa0.x + b.y * wa0.y + b.z * wa0.z + b.w * wa0.w;
          ur[bb][h1] += a.x * wa1.x + a.y * wa1.y + a.z * wa1.z + a.w * wa1.w
                      - b.x * wb1.x - b.y * wb1.y - b.z * wb1.z - b.w * wb1.w;
          ui[bb][h1] += a.x * wb1.x + a.y * wb1.y + a.z * wb1.z + a.w * wb1.w
                      + b.x * wa1.x + b.y * wa1.y + b.z * wa1.z + b.w * wa1.w;
        }
      }
    }
  }
#pragma unroll
  for (int bb = 0; bb < 4; bb++) {
    int b = ty + 16 * bb;
#pragma unroll
    for (int hh = 0; hh < 4; hh++) {
      int h = H0 + tx + 16 * hh;
      *(float2*)&pacc[(((size_t)kc * 64 + b) * 512 + h) * 2] = make_float2(ur[bb][hh], ui[bb][hh]);
    }
  }
}

// ---------------- reduce partials + fc1 bias/ReLU + actor/critic head ----------------

__global__ __launch_bounds__(256) void k_head(const float* __restrict__ pacc,
                                              const float* __restrict__ br, const float* __restrict__ bi,
                                              const float* __restrict__ actor_w, const float* __restrict__ actor_b,
                                              const float* __restrict__ critic_w, const float* __restrict__ critic_b,
                                              float* __restrict__ out) {
  __shared__ float urs[512], uis[512];
  int b = blockIdx.x, t = threadIdx.x;
  float s0r = 0, s0i = 0, s1r = 0, s1i = 0;
  for (int kc = 0; kc < 64; kc++) {
    float4 v = *(const float4*)&pacc[(((size_t)kc * 64 + b) * 512 + 2 * t) * 2];
    s0r += v.x; s0i += v.y; s1r += v.z; s1i += v.w;
  }
  urs[2 * t]     = fmaxf(s0r + br[2 * t], 0.f);
  uis[2 * t]     = fmaxf(s0i + bi[2 * t], 0.f);
  urs[2 * t + 1] = fmaxf(s1r + br[2 * t + 1], 0.f);
  uis[2 * t + 1] = fmaxf(s1i + bi[2 * t + 1], 0.f);
  __syncthreads();
  if (t < 33) {
    const float* w = (t < 32) ? (actor_w + t * 1024) : critic_w;
    float acc = (t < 32) ? actor_b[t] : critic_b[0];
    for (int k = 0; k < 512; k++)
      acc += urs[k] * w[k] + uis[k] * w[512 + k];
    if (t < 32) out[b * 32 + t] = acc;
    else        out[2048 + b] = acc;
  }
}

// ---------------- launch ----------------

extern "C" void kernel_launch(void* const* d_in, const int* in_sizes, int n_in,
                              void* d_out, int out_size, void* d_ws, size_t ws_size,
                              hipStream_t stream) {
  const float* xr   = (const float*)d_in[0];
  const float* xi   = (const float*)d_in[1];
  const float* ew   = (const float*)d_in[2];
  const float* c1wr = (const float*)d_in[3];
  const float* c1wi = (const float*)d_in[4];
  const float* c1br = (const float*)d_in[5];
  const float* c1bi = (const float*)d_in[6];
  const float* chw  = (const float*)d_in[7];
  const float* chb  = (const float*)d_in[8];
  const float* f1wr = (const float*)d_in[9];
  const float* f1wi = (const float*)d_in[10];
  const float* f1br = (const float*)d_in[11];
  const float* f1bi = (const float*)d_in[12];
  const float* cw   = (const float*)d_in[13];
  const float* cb   = (const float*)d_in[14];
  const float* aw   = (const float*)d_in[15];
  const float* ab   = (const float*)d_in[16];
  const int*   ei   = (const int*)d_in[17];
  float* out = (float*)d_out;

  char* ws = (char*)d_ws;
  size_t off = 0;
  auto alloc = [&](size_t bytes) { char* p = ws + off; off += (bytes + 255) & ~(size_t)255; return p; };
  float* deg      = (float*)alloc((size_t)NN_ * 4);   // zeroed (deg, cnt, fill contiguous)
  int*   cnt      = (int*)  alloc((size_t)NN_ * 4);   // zeroed
  int*   fill     = (int*)  alloc((size_t)NN_ * 4);   // zeroed
  int*   rowstart = (int*)  alloc((size_t)NN_ * 4);
  float* dinv     = (float*)alloc((size_t)NN_ * 4);
  int*   bsum     = (int*)  alloc(1024);
  int*   boff     = (int*)  alloc(1024);
  int*   col_s    = (int*)  alloc((size_t)E_ * 4);
  float* wn_s     = (float*)alloc((size_t)E_ * 4);
  float* zr       = (float*)alloc((size_t)NN_ * 10 * 4);
  float* zi       = (float*)alloc((size_t)NN_ * 10 * 4);
  float* Y        = (float*)alloc((size_t)NN_ * 20 * 4);
  float* T1       = (float*)alloc((size_t)NN_ * 20 * 4);
  // pacc (16 MB) aliases Y+T1 (21 MB): both dead once k_fc1 starts
  float* pacc = Y;

  hipMemsetAsync(deg, 0, (size_t)NN_ * 4 * 3, stream);  // deg, cnt, fill

  k_deg_hist<<<E_ / 256, 256, 0, stream>>>(ei, ew, deg, cnt);
  k_dinv<<<NN_ / 256, 256, 0, stream>>>(deg, dinv);
  k_scan_a<<<256, 256, 0, stream>>>(cnt, bsum);
  k_scan_b<<<1, 256, 0, stream>>>(bsum, boff);
  k_scan_c<<<256, 256, 0, stream>>>(cnt, boff, rowstart);
  k_build<<<E_ / 256, 256, 0, stream>>>(ei, ew, dinv, rowstart, fill, col_s, wn_s);
  k_conv1<<<NN_ / 256, 256, 0, stream>>>(xr, xi, c1wr, c1wi, c1br, c1bi, Y);
  k_lap1<<<NN_ / 256, 256, 0, stream>>>(Y, col_s, wn_s, rowstart, cnt, T1);
  k_lap2cheb<<<NN_ / 256, 256, 0, stream>>>(Y, T1, col_s, wn_s, rowstart, cnt, chw, chb, zr, zi);
  k_fc1<<<dim3(8, 64), 256, 0, stream>>>(zr, zi, f1wr, f1wi, pacc);
  k_head<<<B_, 256, 0, stream>>>(pacc, f1br, f1bi, aw, ab, cw, cb, out);
}

// Round 5
// 623.616 us; speedup vs baseline: 2.0260x; 1.2092x over previous
//
#include <hip/hip_runtime.h>

#define NN_ 131072
#define E_  2097152
#define B_  64
#define K_  20480
#define H_  512
#define EPS_ 1e-6f
#define DEGSCALE 4194304.0f      // 2^22
#define DEGINV   (1.0f / 4194304.0f)

// ---------------- graph preprocessing ----------------
// R5: deg+cnt fused into ONE 64-bit atomic per edge (was two 32-bit: 130 MB
// atomic write-through @ 32B each -> halved). deg fixed-point Q.22 in low
// word, count in high word; max row-degree*2^22 << 2^32 so no carry.

__global__ __launch_bounds__(256) void k_deg_hist(const int* __restrict__ ei, const float* __restrict__ ew,
                                                  unsigned long long* __restrict__ pack) {
  int e = blockIdx.x * 256 + threadIdx.x;
  if (e >= E_) return;
  int r = ei[e];
  unsigned long long q = (unsigned long long)(unsigned)(ew[e] * DEGSCALE + 0.5f);
  atomicAdd(&pack[r], (1ULL << 32) | q);
}

__global__ __launch_bounds__(256) void k_dinv(const unsigned long long* __restrict__ pack,
                                              float* __restrict__ dinv, int* __restrict__ cnt) {
  int n = blockIdx.x * 256 + threadIdx.x;
  if (n >= NN_) return;
  unsigned long long p = pack[n];
  float d = (float)(unsigned)(p & 0xFFFFFFFFULL) * DEGINV;
  dinv[n] = (d > 0.f) ? rsqrtf(d + EPS_) : 0.f;
  cnt[n] = (int)(p >> 32);
}

__global__ __launch_bounds__(256) void k_scan_a(const int* __restrict__ cnt, int* __restrict__ bsum) {
  __shared__ int s[256];
  int t = threadIdx.x, b = blockIdx.x;
  s[t] = cnt[b * 512 + t] + cnt[b * 512 + 256 + t];
  __syncthreads();
  for (int off = 128; off > 0; off >>= 1) {
    if (t < off) s[t] += s[t + off];
    __syncthreads();
  }
  if (t == 0) bsum[b] = s[0];
}

__global__ __launch_bounds__(256) void k_scan_b(const int* __restrict__ bsum, int* __restrict__ boff) {
  __shared__ int s[256];
  int t = threadIdx.x;
  int orig = bsum[t];
  s[t] = orig;
  __syncthreads();
  for (int off = 1; off < 256; off <<= 1) {
    int v = (t >= off) ? s[t - off] : 0;
    __syncthreads();
    s[t] += v;
    __syncthreads();
  }
  boff[t] = s[t] - orig;   // exclusive
}

__global__ __launch_bounds__(256) void k_scan_c(const int* __restrict__ cnt, const int* __restrict__ boff,
                                                int* __restrict__ rowstart) {
  __shared__ int s[256];
  int t = threadIdx.x, b = blockIdx.x;
  int base = b * 512;
  int c0 = cnt[base + 2 * t], c1 = cnt[base + 2 * t + 1];
  int pair = c0 + c1;
  s[t] = pair;
  __syncthreads();
  for (int off = 1; off < 256; off <<= 1) {
    int v = (t >= off) ? s[t - off] : 0;
    __syncthreads();
    s[t] += v;
    __syncthreads();
  }
  int excl = s[t] - pair + boff[b];
  rowstart[base + 2 * t] = excl;
  rowstart[base + 2 * t + 1] = excl + c0;
}

// R5: CSR record packed (col, w) -> single 8B scattered store (was 2x 4B)

__global__ __launch_bounds__(256) void k_build(const int* __restrict__ ei, const float* __restrict__ ew,
                                               const float* __restrict__ dinv, const int* __restrict__ rowstart,
                                               int* __restrict__ fill, int2* __restrict__ ecsr) {
  int e = blockIdx.x * 256 + threadIdx.x;
  if (e >= E_) return;
  int r = ei[e], c = ei[E_ + e];
  float w = ew[e] * dinv[r] * dinv[c];
  int pos = rowstart[r] + atomicAdd(&fill[r], 1);
  ecsr[pos] = make_int2(c, __float_as_int(w));
}

// ---------------- conv1 (complex 1x1 conv + ReLU) ----------------
// Y layout: [NN][20]  (0..9 real, 10..19 imag)

__global__ __launch_bounds__(256) void k_conv1(const float* __restrict__ xr, const float* __restrict__ xi,
                                               const float* __restrict__ wr_g, const float* __restrict__ wi_g,
                                               const float* __restrict__ br_g, const float* __restrict__ bi_g,
                                               float* __restrict__ Y) {
  __shared__ float wr[100], wi[100], br[10], bi[10];
  int t = threadIdx.x;
  if (t < 100) { wr[t] = wr_g[t]; wi[t] = wi_g[t]; }
  if (t < 10)  { br[t] = br_g[t]; bi[t] = bi_g[t]; }
  __syncthreads();
  int n = blockIdx.x * 256 + t;
  float xrv[10], xiv[10];
  const float2* a = (const float2*)(xr + (size_t)n * 10);
  const float2* b2 = (const float2*)(xi + (size_t)n * 10);
#pragma unroll
  for (int i = 0; i < 5; i++) {
    float2 v = a[i];  xrv[2 * i] = v.x; xrv[2 * i + 1] = v.y;
    float2 u = b2[i]; xiv[2 * i] = u.x; xiv[2 * i + 1] = u.y;
  }
  float out[20];
#pragma unroll
  for (int c = 0; c < 10; c++) {
    float ar = br[c], ai = bi[c];
#pragma unroll
    for (int tt = 0; tt < 10; tt++) {
      float wrc = wr[c * 10 + tt], wic = wi[c * 10 + tt];
      ar += xrv[tt] * wrc - xiv[tt] * wic;
      ai += xrv[tt] * wic + xiv[tt] * wrc;
    }
    out[c] = fmaxf(ar, 0.f);
    out[10 + c] = fmaxf(ai, 0.f);
  }
  float4* yp = (float4*)(Y + (size_t)n * 20);
#pragma unroll
  for (int i = 0; i < 5; i++)
    yp[i] = make_float4(out[4 * i], out[4 * i + 1], out[4 * i + 2], out[4 * i + 3]);
}

// ---------------- Laplacian pass 1: T1 = Y - S(Y) ----------------

__global__ __launch_bounds__(256) void k_lap1(const float* __restrict__ Y, const int2* __restrict__ ecsr,
                                              const int* __restrict__ rowstart,
                                              const int* __restrict__ cnt, float* __restrict__ T1) {
  int n = blockIdx.x * 256 + threadIdx.x;
  float acc[20];
#pragma unroll
  for (int j = 0; j < 20; j++) acc[j] = 0.f;
  int e0 = rowstart[n], ec = cnt[n];
  for (int i = 0; i < ec; i++) {
    int2 rec = ecsr[e0 + i];
    int c = rec.x;
    float w = __int_as_float(rec.y);
    const float4* yp = (const float4*)(Y + (size_t)c * 20);
#pragma unroll
    for (int q = 0; q < 5; q++) {
      float4 v = yp[q];
      acc[4 * q]     += w * v.x;
      acc[4 * q + 1] += w * v.y;
      acc[4 * q + 2] += w * v.z;
      acc[4 * q + 3] += w * v.w;
    }
  }
  const float4* yn = (const float4*)(Y + (size_t)n * 20);
  float4* tp = (float4*)(T1 + (size_t)n * 20);
#pragma unroll
  for (int q = 0; q < 5; q++) {
    float4 v = yn[q];
    tp[q] = make_float4(v.x - acc[4 * q], v.y - acc[4 * q + 1],
                        v.z - acc[4 * q + 2], v.w - acc[4 * q + 3]);
  }
}

// ---------------- Laplacian pass 2 + Chebyshev combine + ReLU ----------------

__global__ __launch_bounds__(256) void k_lap2cheb(const float* __restrict__ Y, const float* __restrict__ T1,
                                                  const int2* __restrict__ ecsr,
                                                  const int* __restrict__ rowstart, const int* __restrict__ cnt,
                                                  const float* __restrict__ cw_g, const float* __restrict__ cb_g,
                                                  float* __restrict__ zr, float* __restrict__ zi) {
  __shared__ float cw[300], cb[10];
  int t = threadIdx.x;
  for (int j = t; j < 300; j += 256) cw[j] = cw_g[j];   // 300 > blockDim: strided load
  if (t < 10)  cb[t] = cb_g[t];
  __syncthreads();
  int n = blockIdx.x * 256 + t;
  float acc[20];
#pragma unroll
  for (int j = 0; j < 20; j++) acc[j] = 0.f;
  int e0 = rowstart[n], ec = cnt[n];
  for (int i = 0; i < ec; i++) {
    int2 rec = ecsr[e0 + i];
    int c = rec.x;
    float w = __int_as_float(rec.y);
    const float4* tp = (const float4*)(T1 + (size_t)c * 20);
#pragma unroll
    for (int q = 0; q < 5; q++) {
      float4 v = tp[q];
      acc[4 * q]     += w * v.x;
      acc[4 * q + 1] += w * v.y;
      acc[4 * q + 2] += w * v.z;
      acc[4 * q + 3] += w * v.w;
    }
  }
  float t0[20], t1v[20], t2[20];
  const float4* yn = (const float4*)(Y + (size_t)n * 20);
  const float4* tn = (const float4*)(T1 + (size_t)n * 20);
#pragma unroll
  for (int q = 0; q < 5; q++) {
    float4 v = yn[q]; t0[4 * q] = v.x; t0[4 * q + 1] = v.y; t0[4 * q + 2] = v.z; t0[4 * q + 3] = v.w;
    float4 u = tn[q]; t1v[4 * q] = u.x; t1v[4 * q + 1] = u.y; t1v[4 * q + 2] = u.z; t1v[4 * q + 3] = u.w;
  }
#pragma unroll
  for (int j = 0; j < 20; j++) t2[j] = 2.f * (t1v[j] - acc[j]) - t0[j];

  float outr[10], outi[10];
#pragma unroll
  for (int o = 0; o < 10; o++) { outr[o] = cb[o]; outi[o] = 0.f; }
#pragma unroll
  for (int i = 0; i < 10; i++) {
#pragma unroll
    for (int o = 0; o < 10; o++) {
      float w0 = cw[i * 10 + o], w1 = cw[100 + i * 10 + o], w2 = cw[200 + i * 10 + o];
      outr[o] += t0[i] * w0 + t1v[i] * w1 + t2[i] * w2;
      outi[o] += t0[10 + i] * w0 + t1v[10 + i] * w1 + t2[10 + i] * w2;
    }
  }
  float2* zrp = (float2*)(zr + (size_t)n * 10);
  float2* zip = (float2*)(zi + (size_t)n * 10);
#pragma unroll
  for (int q = 0; q < 5; q++) {
    zrp[q] = make_float2(fmaxf(outr[2 * q], 0.f), fmaxf(outr[2 * q + 1], 0.f));
    zip[q] = make_float2(fmaxf(outi[2 * q], 0.f), fmaxf(outi[2 * q + 1], 0.f));
  }
}

// ---------------- fc1 complex GEMM (split-K, partials) ----------------
// grid (8 h-tiles, 64 k-chunks); tile 64b x 64h; chunk = 320 = 10 iters of 32
// pacc layout: [kc][b][h][2]
// R4: spill fix — unroll-1 on it/j0 loops, hh split in halves.

__global__ __launch_bounds__(256) void k_fc1(const float* __restrict__ zr, const float* __restrict__ zi,
                                             const float* __restrict__ Wr, const float* __restrict__ Wi,
                                             float* __restrict__ pacc) {
  __shared__ float zsr[64][36], zsi[64][36], wsr[64][36], wsi[64][36];
  int t = threadIdx.x;
  int hb = blockIdx.x;          // 0..7
  int kc = blockIdx.y;          // 0..63
  int H0 = hb * 64;
  int tx = t & 15, ty = t >> 4; // tx: h-dim, ty: b-dim (0..15)

  float ur[4][4], ui[4][4];
#pragma unroll
  for (int i = 0; i < 4; i++)
#pragma unroll
    for (int j = 0; j < 4; j++) { ur[i][j] = 0.f; ui[i][j] = 0.f; }

#pragma unroll 1
  for (int it = 0; it < 10; it++) {
    int JJ = kc * 320 + it * 32;
    __syncthreads();
#pragma unroll
    for (int l = 0; l < 2; l++) {
      int f = t + l * 256;          // float4 id 0..511
      int row = f >> 3;             // 0..63
      int j4 = (f & 7) << 2;        // 0..28
      float4 vz = *(const float4*)(zr + row * K_ + JJ + j4);
      float4 vi = *(const float4*)(zi + row * K_ + JJ + j4);
      float4 vr = *(const float4*)(Wr + (H0 + row) * K_ + JJ + j4);
      float4 vw = *(const float4*)(Wi + (H0 + row) * K_ + JJ + j4);
      *(float4*)&zsr[row][j4] = vz;
      *(float4*)&zsi[row][j4] = vi;
      *(float4*)&wsr[row][j4] = vr;
      *(float4*)&wsi[row][j4] = vw;
    }
    __syncthreads();
#pragma unroll 1
    for (int j0 = 0; j0 < 32; j0 += 4) {
      float4 za[4], zb[4];
#pragma unroll
      for (int bb = 0; bb < 4; bb++) {
        za[bb] = *(const float4*)&zsr[ty + 16 * bb][j0];
        zb[bb] = *(const float4*)&zsi[ty + 16 * bb][j0];
      }
#pragma unroll
      for (int hp = 0; hp < 2; hp++) {
        int h0 = 2 * hp, h1 = 2 * hp + 1;
        float4 wa0 = *(const float4*)&wsr[tx + 16 * h0][j0];
        float4 wb0 = *(const float4*)&wsi[tx + 16 * h0][j0];
        float4 wa1 = *(const float4*)&wsr[tx + 16 * h1][j0];
        float4 wb1 = *(const float4*)&wsi[tx + 16 * h1][j0];
#pragma unroll
        for (int bb = 0; bb < 4; bb++) {
          float4 a = za[bb], b = zb[bb];
          ur[bb][h0] += a.x * wa0.x + a.y * wa0.y + a.z * wa0.z + a.w * wa0.w
                      - b.x * wb0.x - b.y * wb0.y - b.z * wb0.z - b.w * wb0.w;
          ui[bb][h0] += a.x * wb0.x + a.y * wb0.y + a.z * wb0.z + a.w * wb0.w
                      + b.x * wa0.x + b.y * wa0.y + b.z * wa0.z + b.w * wa0.w;
          ur[bb][h1] += a.x * wa1.x + a.y * wa1.y + a.z * wa1.z + a.w * wa1.w
                      - b.x * wb1.x - b.y * wb1.y - b.z * wb1.z - b.w * wb1.w;
          ui[bb][h1] += a.x * wb1.x + a.y * wb1.y + a.z * wb1.z + a.w * wb1.w
                      + b.x * wa1.x + b.y * wa1.y + b.z * wa1.z + b.w * wa1.w;
        }
      }
    }
  }
#pragma unroll
  for (int bb = 0; bb < 4; bb++) {
    int b = ty + 16 * bb;
#pragma unroll
    for (int hh = 0; hh < 4; hh++) {
      int h = H0 + tx + 16 * hh;
      *(float2*)&pacc[(((size_t)kc * 64 + b) * 512 + h) * 2] = make_float2(ur[bb][hh], ui[bb][hh]);
    }
  }
}

// ---------------- reduce partials + fc1 bias/ReLU + actor/critic head ----------------

__global__ __launch_bounds__(256) void k_head(const float* __restrict__ pacc,
                                              const float* __restrict__ br, const float* __restrict__ bi,
                                              const float* __restrict__ actor_w, const float* __restrict__ actor_b,
                                              const float* __restrict__ critic_w, const float* __restrict__ critic_b,
                                              float* __restrict__ out) {
  __shared__ float urs[512], uis[512];
  int b = blockIdx.x, t = threadIdx.x;
  float s0r = 0, s0i = 0, s1r = 0, s1i = 0;
  for (int kc = 0; kc < 64; kc++) {
    float4 v = *(const float4*)&pacc[(((size_t)kc * 64 + b) * 512 + 2 * t) * 2];
    s0r += v.x; s0i += v.y; s1r += v.z; s1i += v.w;
  }
  urs[2 * t]     = fmaxf(s0r + br[2 * t], 0.f);
  uis[2 * t]     = fmaxf(s0i + bi[2 * t], 0.f);
  urs[2 * t + 1] = fmaxf(s1r + br[2 * t + 1], 0.f);
  uis[2 * t + 1] = fmaxf(s1i + bi[2 * t + 1], 0.f);
  __syncthreads();
  if (t < 33) {
    const float* w = (t < 32) ? (actor_w + t * 1024) : critic_w;
    float acc = (t < 32) ? actor_b[t] : critic_b[0];
    for (int k = 0; k < 512; k++)
      acc += urs[k] * w[k] + uis[k] * w[512 + k];
    if (t < 32) out[b * 32 + t] = acc;
    else        out[2048 + b] = acc;
  }
}

// ---------------- launch ----------------

extern "C" void kernel_launch(void* const* d_in, const int* in_sizes, int n_in,
                              void* d_out, int out_size, void* d_ws, size_t ws_size,
                              hipStream_t stream) {
  const float* xr   = (const float*)d_in[0];
  const float* xi   = (const float*)d_in[1];
  const float* ew   = (const float*)d_in[2];
  const float* c1wr = (const float*)d_in[3];
  const float* c1wi = (const float*)d_in[4];
  const float* c1br = (const float*)d_in[5];
  const float* c1bi = (const float*)d_in[6];
  const float* chw  = (const float*)d_in[7];
  const float* chb  = (const float*)d_in[8];
  const float* f1wr = (const float*)d_in[9];
  const float* f1wi = (const float*)d_in[10];
  const float* f1br = (const float*)d_in[11];
  const float* f1bi = (const float*)d_in[12];
  const float* cw   = (const float*)d_in[13];
  const float* cb   = (const float*)d_in[14];
  const float* aw   = (const float*)d_in[15];
  const float* ab   = (const float*)d_in[16];
  const int*   ei   = (const int*)d_in[17];
  float* out = (float*)d_out;

  char* ws = (char*)d_ws;
  size_t off = 0;
  auto alloc = [&](size_t bytes) { char* p = ws + off; off += (bytes + 255) & ~(size_t)255; return p; };
  unsigned long long* pack = (unsigned long long*)alloc((size_t)NN_ * 8);  // memset 0 (pack+fill contiguous)
  int*   fill     = (int*)  alloc((size_t)NN_ * 4);                        // memset 0
  int*   cnt      = (int*)  alloc((size_t)NN_ * 4);
  int*   rowstart = (int*)  alloc((size_t)NN_ * 4);
  float* dinv     = (float*)alloc((size_t)NN_ * 4);
  int*   bsum     = (int*)  alloc(1024);
  int*   boff     = (int*)  alloc(1024);
  int2*  ecsr     = (int2*) alloc((size_t)E_ * 8);
  float* zr       = (float*)alloc((size_t)NN_ * 10 * 4);
  float* zi       = (float*)alloc((size_t)NN_ * 10 * 4);
  float* Y        = (float*)alloc((size_t)NN_ * 20 * 4);
  float* T1       = (float*)alloc((size_t)NN_ * 20 * 4);
  // pacc (16 MB) aliases Y+T1 (21 MB): both dead once k_fc1 starts
  float* pacc = Y;

  hipMemsetAsync(pack, 0, (size_t)NN_ * 8 + (size_t)NN_ * 4, stream);  // pack, fill

  k_deg_hist<<<E_ / 256, 256, 0, stream>>>(ei, ew, pack);
  k_dinv<<<NN_ / 256, 256, 0, stream>>>(pack, dinv, cnt);
  k_scan_a<<<256, 256, 0, stream>>>(cnt, bsum);
  k_scan_b<<<1, 256, 0, stream>>>(bsum, boff);
  k_scan_c<<<256, 256, 0, stream>>>(cnt, boff, rowstart);
  k_build<<<E_ / 256, 256, 0, stream>>>(ei, ew, dinv, rowstart, fill, ecsr);
  k_conv1<<<NN_ / 256, 256, 0, stream>>>(xr, xi, c1wr, c1wi, c1br, c1bi, Y);
  k_lap1<<<NN_ / 256, 256, 0, stream>>>(Y, ecsr, rowstart, cnt, T1);
  k_lap2cheb<<<NN_ / 256, 256, 0, stream>>>(Y, T1, ecsr, rowstart, cnt, chw, chb, zr, zi);
  k_fc1<<<dim3(8, 64), 256, 0, stream>>>(zr, zi, f1wr, f1wi, pacc);
  k_head<<<B_, 256, 0, stream>>>(pacc, f1br, f1bi, aw, ab, cw, cb, out);
}